// Round 5
// baseline (994.705 us; speedup 1.0000x reference)
//
#include <hip/hip_runtime.h>
#include <hip/hip_bf16.h>
#include <hip/hip_cooperative_groups.h>

namespace cg = cooperative_groups;

typedef unsigned short u16;
typedef unsigned int u32;
typedef __attribute__((ext_vector_type(4))) float f32x4;
typedef __attribute__((ext_vector_type(8))) short bf16x8;

#define DEVI static __device__ __forceinline__

DEVI u16 f2bf(float f) {
  u32 u = __builtin_bit_cast(u32, f);
  u += 0x7fffu + ((u >> 16) & 1u);
  return (u16)(u >> 16);
}

DEVI void gload_lds16(const void* g, void* l) {
  __builtin_amdgcn_global_load_lds(
      (const __attribute__((address_space(1))) u32*)g,
      (__attribute__((address_space(3))) u32*)l, 16, 0, 0);
}

template<int N> DEVI void wait_vm() {
  if constexpr (N == 4)       asm volatile("s_waitcnt vmcnt(4)" ::: "memory");
  else if constexpr (N == 9)  asm volatile("s_waitcnt vmcnt(9)" ::: "memory");
  else if constexpr (N == 10) asm volatile("s_waitcnt vmcnt(10)" ::: "memory");
  else                        asm volatile("s_waitcnt vmcnt(0)" ::: "memory");
}
DEVI void lgkm_barrier() {
  asm volatile("s_waitcnt lgkmcnt(0)\n\ts_barrier" ::: "memory");
}

// ---------------------------------------------------------------------------
// One GEMM phase: C[64 x BN] = A[m0:m0+64, 0:K] @ Bt[BN][K]^T (bf16 Bt).
// 512 thr = 8 waves, 1x8 wave grid. A reg-staged (fp32->bf16) -> XOR-swizzled
// LDS dbuf; B per-wave slice via global_load_lds (inverse-swizzled source).
// Counted vmcnt; one lgkmcnt(0)+s_barrier per K-step.
// EPI: 0 = bf16 transposed outh[n][M]+m; 1 = bn2(relu(acc+b1)) fp32;
// 2 = acc+b2 fp32.
// ---------------------------------------------------------------------------
template<int BN, bool AF32, int EPI>
__device__ __forceinline__
void gemm_phase(const void* __restrict__ Ap, const u16* __restrict__ Bt,
                const int K, const int M,
                float* __restrict__ outf, u16* __restrict__ outh,
                const float* e0, const float* e1, const float* e2,
                const float* e3, const float* e4,
                char* smem, const int m0, const int tid)
{
  constexpr int BM = 64, BK = 64;
  constexpr int TN = BN / 8;            // 64 | 16
  constexpr int MF = 4, NF = TN / 16;   // 4 x (4|1) fragments
  constexpr int ABYTES = BM * BK * 2;   // 8 KiB
  constexpr int SLICE = TN * BK * 2;    // 8 KiB | 2 KiB
  constexpr int LB = SLICE / 1024;      // 8 | 2 gload_lds per lane
  constexpr int VM = (AF32 ? 2 : 1) + LB;

  const int w = tid >> 6, l = tid & 63;
  const int l15 = l & 15, l4 = l >> 4;
  const int NT = K / BK;

  const int ar = tid >> 3, ac = tid & 7;
  const int apos = ar * 128 + ((ac ^ (ar & 7)) << 4);
  const size_t Abase = (size_t)(m0 + ar) * K + (size_t)ac * 8;

  char* const bslice = smem + 2 * ABYTES + w * SLICE;

  f32x4 acc[MF][NF];
#pragma unroll
  for (int i = 0; i < MF; ++i)
#pragma unroll
    for (int j = 0; j < NF; ++j) acc[i][j] = (f32x4){0.f, 0.f, 0.f, 0.f};

  f32x4 av0, av1;
  uint4 ah;

  auto issueA = [&](int t) {
    if constexpr (AF32) {
      const float* p = (const float*)Ap + Abase + (size_t)t * BK;
      av0 = *(const f32x4*)p;
      av1 = *(const f32x4*)(p + 4);
    } else {
      const u16* p = (const u16*)Ap + Abase + (size_t)t * BK;
      ah = *(const uint4*)p;
    }
  };
  auto writeA = [&](int nb) {
    uint4 pk;
    if constexpr (AF32) {
      pk.x = (u32)f2bf(av0[0]) | ((u32)f2bf(av0[1]) << 16);
      pk.y = (u32)f2bf(av0[2]) | ((u32)f2bf(av0[3]) << 16);
      pk.z = (u32)f2bf(av1[0]) | ((u32)f2bf(av1[1]) << 16);
      pk.w = (u32)f2bf(av1[2]) | ((u32)f2bf(av1[3]) << 16);
    } else {
      pk = ah;
    }
    *(uint4*)(smem + nb * ABYTES + apos) = pk;
  };
  auto issueB = [&](int nb, int t) {
    const char* bsrc = (const char*)Bt +
                       (size_t)(w * TN) * ((size_t)K * 2) + (size_t)(t * BK) * 2;
    char* bd = bslice + nb * (8 * SLICE);
#pragma unroll
    for (int i = 0; i < LB; ++i) {
      const int p = i * 1024 + l * 16;
      const int nl = p >> 7;                 // row within wave slice
      const int q = ((p & 127) >> 4) ^ (nl & 7);
      gload_lds16(bsrc + (size_t)nl * ((size_t)K * 2) + q * 16, bd + i * 1024);
    }
  };
  auto compute = [&](int cb) {
    const char* A = smem + cb * ABYTES;
    const char* Bs = bslice + cb * (8 * SLICE);
#pragma unroll
    for (int kk = 0; kk < 2; ++kk) {
      bf16x8 af[MF];
      uint4 bfr[NF];
#pragma unroll
      for (int mi = 0; mi < MF; ++mi) {
        const int row = mi * 16 + l15;
        af[mi] = *(const bf16x8*)(
            A + row * 128 + (((kk * 4 + l4) ^ (row & 7)) << 4));
      }
#pragma unroll
      for (int ni = 0; ni < NF; ++ni) {
        const int nl = ni * 16 + l15;
        bfr[ni] = *(const uint4*)(
            Bs + nl * 128 + (((kk * 4 + l4) ^ (nl & 7)) << 4));
      }
      __builtin_amdgcn_s_setprio(1);
#pragma unroll
      for (int mi = 0; mi < MF; ++mi)
#pragma unroll
        for (int ni = 0; ni < NF; ++ni)
          acc[mi][ni] = __builtin_amdgcn_mfma_f32_16x16x32_bf16(
              af[mi], __builtin_bit_cast(bf16x8, bfr[ni]), acc[mi][ni],
              0, 0, 0);
      __builtin_amdgcn_s_setprio(0);
    }
  };

  issueA(0);
  issueB(0, 0);
  writeA(0);          // waits only A's loads; B(0) stays in flight
  lgkm_barrier();

  for (int t = 0; t < NT; ++t) {
    const int cur = t & 1, nxt = cur ^ 1;
    const int tn = (t + 1 < NT) ? t + 1 : NT - 1;
    issueA(tn);       // A issued first so writeA's implicit wait = vmcnt(LB)
    issueB(nxt, tn);
    wait_vm<VM>();    // B(t) complete; A(t+1)/B(t+1) remain in flight
    compute(cur);
    writeA(nxt);
    lgkm_barrier();
  }

  const int mrow0 = m0 + l4 * 4;
#pragma unroll
  for (int ni = 0; ni < NF; ++ni) {
    const int n = w * TN + ni * 16 + l15;
    if constexpr (EPI == 0) {
#pragma unroll
      for (int mi = 0; mi < MF; ++mi) {
        const int m = mrow0 + mi * 16;
        ushort4 o;
        o.x = f2bf(acc[mi][ni][0]);
        o.y = f2bf(acc[mi][ni][1]);
        o.z = f2bf(acc[mi][ni][2]);
        o.w = f2bf(acc[mi][ni][3]);
        *(ushort4*)(outh + (size_t)n * M + m) = o;
      }
    } else if constexpr (EPI == 1) {
      const float b1v = e0[n];
      const float sc = e1[n] * rsqrtf(e4[n] + 1e-5f);
      const float sh = e2[n] - e3[n] * sc;
#pragma unroll
      for (int mi = 0; mi < MF; ++mi)
#pragma unroll
        for (int r = 0; r < 4; ++r) {
          float s = fmaxf(acc[mi][ni][r] + b1v, 0.f);
          outf[(size_t)(mrow0 + mi * 16 + r) * BN + n] = s * sc + sh;
        }
    } else {
      const float b2v = e0[n];
#pragma unroll
      for (int mi = 0; mi < MF; ++mi)
#pragma unroll
        for (int r = 0; r < 4; ++r)
          outf[(size_t)(mrow0 + mi * 16 + r) * BN + n] = acc[mi][ni][r] + b2v;
    }
  }
}

// ---------------------------------------------------------------------------
// Fused whole-net cooperative kernel. grid=256 x 512thr, 144 KiB LDS,
// 1 block/CU. Phases separated by grid.sync().
// ---------------------------------------------------------------------------
__global__ __launch_bounds__(512, 2)
void fused_gcn(const float* __restrict__ x, const float* __restrict__ a,
               const float* __restrict__ w1, const float* __restrict__ b1,
               const float* __restrict__ w2, const float* __restrict__ b2,
               const float* __restrict__ g1, const float* __restrict__ be1,
               const float* __restrict__ rm1, const float* __restrict__ rv1,
               const float* __restrict__ g2, const float* __restrict__ be2,
               const float* __restrict__ rm2, const float* __restrict__ rv2,
               u16* __restrict__ xb, u16* __restrict__ w1t,
               u16* __restrict__ w2t, u16* __restrict__ t_t,
               u16* __restrict__ z_t, float* __restrict__ x2,
               float* __restrict__ x1)
{
  __shared__ char smem[147456];        // 16K A dbuf + 128K B slices
  const int tid = threadIdx.x;
  const int bid = blockIdx.x;
  const int gtid = bid * 512 + tid;

  // ---- phase B0: xb = bn1(x) -> bf16 ----
#pragma unroll
  for (int it = 0; it < 8; ++it) {
    const size_t i8 = ((size_t)(it * 131072 + gtid)) * 8;
    const f32x4 v0 = *(const f32x4*)(x + i8);
    const f32x4 v1 = *(const f32x4*)(x + i8 + 4);
    const int f0 = (int)(i8 & 511);
    u16 u[8];
#pragma unroll
    for (int e = 0; e < 8; ++e) {
      const int f = f0 + e;
      const float sc = g1[f] * rsqrtf(rv1[f] + 1e-5f);
      const float v = (e < 4) ? v0[e] : v1[e - 4];
      u[e] = f2bf((v - rm1[f]) * sc + be1[f]);
    }
    uint4 o;
    o.x = (u32)u[0] | ((u32)u[1] << 16);
    o.y = (u32)u[2] | ((u32)u[3] << 16);
    o.z = (u32)u[4] | ((u32)u[5] << 16);
    o.w = (u32)u[6] | ((u32)u[7] << 16);
    *(uint4*)(xb + i8) = o;
  }
  // ---- phase B0b: weight transposes ----
#pragma unroll
  for (int it = 0; it < 2; ++it) {
    const int o = it * 131072 + gtid;
    w1t[o] = f2bf(w1[(o & 511) * 512 + (o >> 9)]);
  }
  if (gtid < 65536)
    w2t[gtid] = f2bf(w2[(gtid & 511) * 128 + (gtid >> 9)]);
  cg::this_grid().sync();

  const int m0 = bid * 64;

  // P1: t = xb @ w1t -> t_t[h][node]
  gemm_phase<512, false, 0>(xb, w1t, 512, 16384, nullptr, t_t,
                            nullptr, nullptr, nullptr, nullptr, nullptr,
                            smem, m0, tid);
  cg::this_grid().sync();

  // P2: x2 = bn2(relu(a @ t + b1))
  gemm_phase<512, true, 1>(a, t_t, 16384, 16384, x2, nullptr,
                           b1, g2, be2, rm2, rv2, smem, m0, tid);
  cg::this_grid().sync();

  // P3: z = x2 @ w2t -> z_t[c][node]
  gemm_phase<128, true, 0>(x2, w2t, 512, 16384, nullptr, z_t,
                           nullptr, nullptr, nullptr, nullptr, nullptr,
                           smem, m0, tid);
  cg::this_grid().sync();

  // P4: x1 = a @ z + b2
  gemm_phase<128, true, 2>(a, z_t, 16384, 16384, x1, nullptr,
                           b2, nullptr, nullptr, nullptr, nullptr,
                           smem, m0, tid);
}

// ---------------------------------------------------------------------------
// Fallback path (non-cooperative), round-3 structure via the same gemm_phase.
// ---------------------------------------------------------------------------
template<int BN, bool AF32, int EPI>
__global__ __launch_bounds__(512, 2)
void gemm_bt(const void* __restrict__ Ap, const u16* __restrict__ Bt,
             const int K, const int M, float* __restrict__ outf,
             u16* __restrict__ outh, const float* e0, const float* e1,
             const float* e2, const float* e3, const float* e4)
{
  __shared__ char smem[2 * 8192 + 16 * (BN / 8) * 64 * 2];
  gemm_phase<BN, AF32, EPI>(Ap, Bt, K, M, outf, outh, e0, e1, e2, e3, e4,
                            smem, blockIdx.x * 64, threadIdx.x);
}

__global__ __launch_bounds__(256)
void bn1_cast_k(const float* __restrict__ x, const float* __restrict__ g,
                const float* __restrict__ be, const float* __restrict__ rm,
                const float* __restrict__ rv, u16* __restrict__ out)
{
  const size_t i8 = ((size_t)blockIdx.x * 256 + threadIdx.x) * 8;
  const f32x4 v0 = *(const f32x4*)(x + i8);
  const f32x4 v1 = *(const f32x4*)(x + i8 + 4);
  const int f0 = (int)(i8 & 511);
  u16 u[8];
#pragma unroll
  for (int e = 0; e < 8; ++e) {
    const int f = f0 + e;
    const float sc = g[f] * rsqrtf(rv[f] + 1e-5f);
    const float v = (e < 4) ? v0[e] : v1[e - 4];
    u[e] = f2bf((v - rm[f]) * sc + be[f]);
  }
  uint4 o;
  o.x = (u32)u[0] | ((u32)u[1] << 16);
  o.y = (u32)u[2] | ((u32)u[3] << 16);
  o.z = (u32)u[4] | ((u32)u[5] << 16);
  o.w = (u32)u[6] | ((u32)u[7] << 16);
  *(uint4*)(out + i8) = o;
}

__global__ __launch_bounds__(256)
void tcvt_k(const float* __restrict__ in, u16* __restrict__ out, int rowlen)
{
  const int o = blockIdx.x * 256 + threadIdx.x;
  out[o] = f2bf(in[(size_t)(o & 511) * rowlen + (o >> 9)]);
}

// ---------------------------------------------------------------------------
extern "C" void kernel_launch(void* const* d_in, const int* in_sizes, int n_in,
                              void* d_out, int out_size, void* d_ws, size_t ws_size,
                              hipStream_t stream)
{
  const float* x   = (const float*)d_in[0];
  const float* a   = (const float*)d_in[1];
  const float* w1  = (const float*)d_in[2];
  const float* b1  = (const float*)d_in[3];
  const float* w2  = (const float*)d_in[4];
  const float* b2  = (const float*)d_in[5];
  const float* g1  = (const float*)d_in[6];
  const float* be1 = (const float*)d_in[7];
  const float* rm1 = (const float*)d_in[8];
  const float* rv1 = (const float*)d_in[9];
  const float* g2  = (const float*)d_in[10];
  const float* be2 = (const float*)d_in[11];
  const float* rm2 = (const float*)d_in[12];
  const float* rv2 = (const float*)d_in[13];

  constexpr int N = 16384, F = 512, H = 512, C = 128;
  float* x1 = (float*)d_out;                      // [N][C]
  float* x2 = (float*)d_out + (size_t)N * C;      // [N][H]

  char* wsp = (char*)d_ws;
  u16* xb  = (u16*)wsp;  wsp += (size_t)N * F * 2;
  u16* t_t = (u16*)wsp;  wsp += (size_t)H * N * 2;
  u16* z_t = (u16*)wsp;  wsp += (size_t)C * N * 2;
  u16* w1t = (u16*)wsp;  wsp += (size_t)H * F * 2;
  u16* w2t = (u16*)wsp;  wsp += (size_t)C * H * 2;

  void* args[] = { (void*)&x, (void*)&a, (void*)&w1, (void*)&b1, (void*)&w2,
                   (void*)&b2, (void*)&g1, (void*)&be1, (void*)&rm1,
                   (void*)&rv1, (void*)&g2, (void*)&be2, (void*)&rm2,
                   (void*)&rv2, (void*)&xb, (void*)&w1t, (void*)&w2t,
                   (void*)&t_t, (void*)&z_t, (void*)&x2, (void*)&x1 };

  hipError_t err = hipLaunchCooperativeKernel(
      (const void*)fused_gcn, dim3(256), dim3(512), args, 0, stream);

  if (err != hipSuccess) {
    // Fallback: separate kernels (no grid sync needed).
    bn1_cast_k<<<(N * F / 8) / 256, 256, 0, stream>>>(x, g1, be1, rm1, rv1, xb);
    tcvt_k<<<(F * H) / 256, 256, 0, stream>>>(w1, w1t, H);
    tcvt_k<<<(H * C) / 256, 256, 0, stream>>>(w2, w2t, C);
    gemm_bt<512, false, 0><<<N / 64, 512, 0, stream>>>(
        xb, w1t, F, N, nullptr, t_t, nullptr, nullptr, nullptr, nullptr, nullptr);
    gemm_bt<512, true, 1><<<N / 64, 512, 0, stream>>>(
        a, t_t, N, N, x2, nullptr, b1, g2, be2, rm2, rv2);
    gemm_bt<128, true, 0><<<N / 64, 512, 0, stream>>>(
        x2, w2t, H, N, nullptr, z_t, nullptr, nullptr, nullptr, nullptr, nullptr);
    gemm_bt<128, true, 2><<<N / 64, 512, 0, stream>>>(
        a, z_t, N, N, x1, nullptr, b2, nullptr, nullptr, nullptr, nullptr);
  }
}

// Round 7
// 882.014 us; speedup vs baseline: 1.1278x; 1.1278x over previous
//
#include <hip/hip_runtime.h>
#include <hip/hip_bf16.h>
#include <hip/hip_cooperative_groups.h>

namespace cg = cooperative_groups;

typedef unsigned short u16;
typedef unsigned int u32;
typedef __attribute__((ext_vector_type(4))) float f32x4;
typedef __attribute__((ext_vector_type(8))) short bf16x8;

#define DEVI static __device__ __forceinline__

DEVI u16 f2bf(float f) {
  u32 u = __builtin_bit_cast(u32, f);
  u += 0x7fffu + ((u >> 16) & 1u);
  return (u16)(u >> 16);
}

DEVI void gload_lds16(const void* g, void* l) {
  __builtin_amdgcn_global_load_lds(
      (const __attribute__((address_space(1))) u32*)g,
      (__attribute__((address_space(3))) u32*)l, 16, 0, 0);
}

template<int N> DEVI void wait_vm() {
  if constexpr (N == 0)       asm volatile("s_waitcnt vmcnt(0)" ::: "memory");
  else if constexpr (N == 4)  asm volatile("s_waitcnt vmcnt(4)" ::: "memory");
  else if constexpr (N == 6)  asm volatile("s_waitcnt vmcnt(6)" ::: "memory");
  else if constexpr (N == 9)  asm volatile("s_waitcnt vmcnt(9)" ::: "memory");
  else if constexpr (N == 12) asm volatile("s_waitcnt vmcnt(12)" ::: "memory");
  else                        asm volatile("s_waitcnt vmcnt(0)" ::: "memory");
}
DEVI void lgkm_barrier() {
  asm volatile("s_waitcnt lgkmcnt(0)\n\ts_barrier" ::: "memory");
}

struct Aregs { f32x4 v0, v1; uint4 h; };

// ---------------------------------------------------------------------------
// One GEMM phase: C[BM rows] = A[m0.., k0..k0+klen] @ Bt[BN][Kfull]^T (bf16).
// 512 thr = 8 waves (1x8). A: fp32->bf16 reg-staged, 2 tiles deep (named
// R0/R1, loop hand-unrolled x2 -> no runtime reg indexing), XOR-swizzled
// ds_write into 2-buf LDS. B: per-wave slice via global_load_lds (inverse-
// swizzled global source), DEPTH tiles deep into DEPTH+1 buffers.
// Counted waits: VMW = DEPTH*(LA+LB) = loads younger than B(t)'s last load
// (iterations t-DEPTH+1..t each issue LA+LB).  One lgkmcnt(0)+s_barrier/step.
// vmcnt(0) drain after the K-loop so no stale gload_lds lands in the next
// phase's LDS. NT must be EVEN (all call sites: 8/256). (BM,BK) in
// {(64,64),(128,32)}: one 16B A chunk per thread.
// EPI 0: bf16 transposed outh[n][M]+m.  EPI 3: fp32 partial to outf+kc*M*BN.
// ---------------------------------------------------------------------------
template<int BM, int BN, int BK, bool AF32, int EPI, int DEPTH>
DEVI void gemm_phase(const void* __restrict__ Ap, const u16* __restrict__ Bt,
                     const int Kfull, const int k0, const int klen,
                     const int M, float* __restrict__ outf,
                     u16* __restrict__ outh, char* smem,
                     const int m0, const int kc, const int tid)
{
  constexpr int TN = BN / 8;
  constexpr int MF = BM / 16, NF = TN / 16, KK = BK / 32;
  constexpr int ABYTES = BM * BK * 2;      // 8 KiB both configs
  constexpr int SLICE = TN * BK * 2;
  constexpr int LB = SLICE / 1024;         // gload_lds per lane per tile
  constexpr int LA = AF32 ? 2 : 1;
  constexpr int NB = DEPTH + 1;
  constexpr int VMW = DEPTH * (LA + LB);   // << fixed: exact younger-count
  constexpr int CPR = BK / 8;
  static_assert(BM * BK == 4096, "one 16B A chunk per thread");

  const int w = tid >> 6, l = tid & 63;
  const int l15 = l & 15, l4 = l >> 4;
  const int NT = klen / BK;

  auto off = [&](int row, int q) -> int {
    if constexpr (BK == 64) return row * 128 + ((q ^ (row & 7)) << 4);
    else                    return row * 64 + ((q ^ ((row >> 1) & 3)) << 4);
  };

  const int ar = tid / CPR, ac = tid % CPR;
  const int apos = off(ar, ac);
  const size_t Abase = (size_t)(m0 + ar) * Kfull + k0 + (size_t)ac * 8;

  char* const bslice = smem + 2 * ABYTES + w * SLICE;

  f32x4 acc[MF][NF];
#pragma unroll
  for (int i = 0; i < MF; ++i)
#pragma unroll
    for (int j = 0; j < NF; ++j) acc[i][j] = (f32x4){0.f, 0.f, 0.f, 0.f};

  Aregs R0, R1;

  auto issueA = [&](Aregs& R, int t) {
    if constexpr (AF32) {
      const float* p = (const float*)Ap + Abase + (size_t)t * BK;
      R.v0 = *(const f32x4*)p;
      R.v1 = *(const f32x4*)(p + 4);
    } else {
      const u16* p = (const u16*)Ap + Abase + (size_t)t * BK;
      R.h = *(const uint4*)p;
    }
  };
  auto writeA = [&](int nb, Aregs& R) {
    uint4 pk;
    if constexpr (AF32) {
      pk.x = (u32)f2bf(R.v0[0]) | ((u32)f2bf(R.v0[1]) << 16);
      pk.y = (u32)f2bf(R.v0[2]) | ((u32)f2bf(R.v0[3]) << 16);
      pk.z = (u32)f2bf(R.v1[0]) | ((u32)f2bf(R.v1[1]) << 16);
      pk.w = (u32)f2bf(R.v1[2]) | ((u32)f2bf(R.v1[3]) << 16);
    } else {
      pk = R.h;
    }
    *(uint4*)(smem + nb * ABYTES + apos) = pk;
  };
  auto issueB = [&](int nb, int t) {
    const char* bsrc = (const char*)Bt +
                       (size_t)(w * TN) * ((size_t)Kfull * 2) +
                       (size_t)(k0 + t * BK) * 2;
    char* bd = bslice + nb * (8 * SLICE);
#pragma unroll
    for (int i = 0; i < LB; ++i) {
      const int p = i * 1024 + l * 16;
      const int nl = (BK == 64) ? (p >> 7) : (p >> 6);
      const int chp = (p & (BK * 2 - 1)) >> 4;
      const int q = (BK == 64) ? (chp ^ (nl & 7)) : (chp ^ ((nl >> 1) & 3));
      gload_lds16(bsrc + (size_t)nl * ((size_t)Kfull * 2) + q * 16,
                  bd + i * 1024);
    }
  };
  auto compute = [&](int ab, int bb) {
    const char* A = smem + ab * ABYTES;
    const char* Bs = bslice + bb * (8 * SLICE);
#pragma unroll
    for (int kk = 0; kk < KK; ++kk) {
      bf16x8 af[MF];
      uint4 bfr[NF];
#pragma unroll
      for (int mi = 0; mi < MF; ++mi)
        af[mi] = *(const bf16x8*)(A + off(mi * 16 + l15, kk * 4 + l4));
#pragma unroll
      for (int ni = 0; ni < NF; ++ni)
        bfr[ni] = *(const uint4*)(Bs + off(ni * 16 + l15, kk * 4 + l4));
      __builtin_amdgcn_s_setprio(1);
#pragma unroll
      for (int mi = 0; mi < MF; ++mi)
#pragma unroll
        for (int ni = 0; ni < NF; ++ni)
          acc[mi][ni] = __builtin_amdgcn_mfma_f32_16x16x32_bf16(
              af[mi], __builtin_bit_cast(bf16x8, bfr[ni]), acc[mi][ni],
              0, 0, 0);
      __builtin_amdgcn_s_setprio(0);
    }
  };

  // prologue: B(0) first (oldest), A(0), A(1), [B(1) if DEPTH=2].
  // writeA's reg-dep wait drains B(0)+A(0); everything younger stays in flight
  issueB(0, 0);
  issueA(R0, 0);
  issueA(R1, NT > 1 ? 1 : 0);
  if constexpr (DEPTH == 2) issueB(1, NT > 1 ? 1 : 0);
  writeA(0, R0);
  lgkm_barrier();

  int bc = 0, bi = DEPTH % NB;
  int t2 = 0;

#define SUBSTEP(RI, RW, ABUF)                                                \
  {                                                                          \
    const int tA = (t2 + 2 < NT) ? t2 + 2 : NT - 1;                          \
    const int tB = (t2 + DEPTH < NT) ? t2 + DEPTH : NT - 1;                  \
    issueA(RI, tA);                                                          \
    issueB(bi, tB);                                                          \
    wait_vm<VMW>();                                                          \
    compute(ABUF, bc);                                                       \
    writeA(ABUF ^ 1, RW);                                                    \
    lgkm_barrier();                                                          \
    bc = (bc + 1 == NB) ? 0 : bc + 1;                                        \
    bi = (bi + 1 == NB) ? 0 : bi + 1;                                        \
    ++t2;                                                                    \
  }

  for (int it = 0; it < NT / 2; ++it) {
    SUBSTEP(R0, R1, 0);   // even t: refill R0(tile t+2); stage R1(tile t+1)
    SUBSTEP(R1, R0, 1);   // odd t
  }
#undef SUBSTEP

  wait_vm<0>();   // drain stale tail gload_lds before LDS is reused

  const int mrow0 = m0 + l4 * 4;
#pragma unroll
  for (int ni = 0; ni < NF; ++ni) {
    const int n = w * TN + ni * 16 + l15;
    if constexpr (EPI == 0) {
#pragma unroll
      for (int mi = 0; mi < MF; ++mi) {
        const int m = mrow0 + mi * 16;
        ushort4 o;
        o.x = f2bf(acc[mi][ni][0]);
        o.y = f2bf(acc[mi][ni][1]);
        o.z = f2bf(acc[mi][ni][2]);
        o.w = f2bf(acc[mi][ni][3]);
        *(ushort4*)(outh + (size_t)n * M + m) = o;
      }
    } else {
      float* Pout = outf + (size_t)kc * ((size_t)M * BN);
#pragma unroll
      for (int mi = 0; mi < MF; ++mi)
#pragma unroll
        for (int r = 0; r < 4; ++r)
          Pout[(size_t)(mrow0 + mi * 16 + r) * BN + n] = acc[mi][ni][r];
    }
  }
}

// block mappings ------------------------------------------------------------
DEVI int map64(int bid) {            // 256 blocks -> 64-row tile, XCD swizzle
  return ((bid & 7) * 32 + (bid >> 3)) * 64;
}
DEVI void map128(int bid, int& m0, int& kc) {  // 128 m-tiles x 2 k-chunks
  kc = bid & 1;                                 // XCD-uniform k-chunk
  const int q = bid >> 1;
  m0 = ((q & 3) * 32 + (q >> 2)) * 128;
}

// ---------------------------------------------------------------------------
// Fused whole-net cooperative kernel: grid 256 x 512 thr, 144 KiB LDS.
// ---------------------------------------------------------------------------
__global__ __launch_bounds__(512, 2)
void fused_gcn(const float* __restrict__ x, const float* __restrict__ a,
               const float* __restrict__ w1, const float* __restrict__ b1,
               const float* __restrict__ w2, const float* __restrict__ b2,
               const float* __restrict__ g1, const float* __restrict__ be1,
               const float* __restrict__ rm1, const float* __restrict__ rv1,
               const float* __restrict__ g2, const float* __restrict__ be2,
               const float* __restrict__ rm2, const float* __restrict__ rv2,
               u16* __restrict__ xb, u16* __restrict__ w1t,
               u16* __restrict__ w2t, u16* __restrict__ t_t,
               u16* __restrict__ z_t, float* __restrict__ P2p,
               float* __restrict__ P4p, float* __restrict__ x2,
               float* __restrict__ x1)
{
  __shared__ char smem[147456];
  const int tid = threadIdx.x;
  const int bid = blockIdx.x;
  const int gtid = bid * 512 + tid;

  // B0: xb = bn1(x) bf16; weight transposes
#pragma unroll
  for (int it = 0; it < 8; ++it) {
    const size_t i8 = ((size_t)(it * 131072 + gtid)) * 8;
    const f32x4 v0 = *(const f32x4*)(x + i8);
    const f32x4 v1 = *(const f32x4*)(x + i8 + 4);
    const int f0 = (int)(i8 & 511);
    u16 u[8];
#pragma unroll
    for (int e = 0; e < 8; ++e) {
      const int f = f0 + e;
      const float sc = g1[f] * rsqrtf(rv1[f] + 1e-5f);
      const float v = (e < 4) ? v0[e] : v1[e - 4];
      u[e] = f2bf((v - rm1[f]) * sc + be1[f]);
    }
    uint4 o;
    o.x = (u32)u[0] | ((u32)u[1] << 16);
    o.y = (u32)u[2] | ((u32)u[3] << 16);
    o.z = (u32)u[4] | ((u32)u[5] << 16);
    o.w = (u32)u[6] | ((u32)u[7] << 16);
    *(uint4*)(xb + i8) = o;
  }
#pragma unroll
  for (int it = 0; it < 2; ++it) {
    const int o = it * 131072 + gtid;
    w1t[o] = f2bf(w1[(o & 511) * 512 + (o >> 9)]);
  }
  if (gtid < 65536)
    w2t[gtid] = f2bf(w2[(gtid & 511) * 128 + (gtid >> 9)]);
  cg::this_grid().sync();

  // P1: t = xb @ w1t -> t_t[h][n]   (DEPTH=1: VMW = 1*(1+8) = 9)
  gemm_phase<64, 512, 64, false, 0, 1>(xb, w1t, 512, 0, 512, 16384,
                                       nullptr, t_t, smem, map64(bid), 0, tid);
  cg::this_grid().sync();

  // P2: partial a @ t (BM=128, k-split 2, DEPTH=2: VMW = 2*(2+4) = 12)
  {
    int m0, kc; map128(bid, m0, kc);
    gemm_phase<128, 512, 32, true, 3, 2>(a, t_t, 16384, kc * 8192, 8192,
                                         16384, P2p, nullptr, smem, m0, kc, tid);
  }
  cg::this_grid().sync();

  // C2: x2 = bn2(relu(P2a + P2b + b1))
#pragma unroll
  for (int it = 0; it < 16; ++it) {
    const size_t i4 = ((size_t)(it * 131072 + gtid)) * 4;
    const f32x4 p0 = *(const f32x4*)(P2p + i4);
    const f32x4 p1 = *(const f32x4*)(P2p + (size_t)16384 * 512 + i4);
    const int f0 = (int)(i4 & 511);
    f32x4 o;
#pragma unroll
    for (int e = 0; e < 4; ++e) {
      const int f = f0 + e;
      float s = fmaxf(p0[e] + p1[e] + b1[f], 0.f);
      const float sc = g2[f] * rsqrtf(rv2[f] + 1e-5f);
      o[e] = s * sc + (be2[f] - rm2[f] * sc);
    }
    *(f32x4*)(x2 + i4) = o;
  }
  cg::this_grid().sync();

  // P3: z = x2 @ w2t -> z_t[c][n]   (DEPTH=1: VMW = 1*(2+2) = 4)
  gemm_phase<64, 128, 64, true, 0, 1>(x2, w2t, 512, 0, 512, 16384,
                                      nullptr, z_t, smem, map64(bid), 0, tid);
  cg::this_grid().sync();

  // P4: partial a @ z (BM=128, k-split 2, DEPTH=2: VMW = 2*(2+1) = 6)
  {
    int m0, kc; map128(bid, m0, kc);
    gemm_phase<128, 128, 32, true, 3, 2>(a, z_t, 16384, kc * 8192, 8192,
                                         16384, P4p, nullptr, smem, m0, kc, tid);
  }
  cg::this_grid().sync();

  // C4: x1 = P4a + P4b + b2
#pragma unroll
  for (int it = 0; it < 4; ++it) {
    const size_t i4 = ((size_t)(it * 131072 + gtid)) * 4;
    const f32x4 p0 = *(const f32x4*)(P4p + i4);
    const f32x4 p1 = *(const f32x4*)(P4p + (size_t)16384 * 128 + i4);
    const int f0 = (int)(i4 & 127);
    f32x4 o;
#pragma unroll
    for (int e = 0; e < 4; ++e) o[e] = p0[e] + p1[e] + b2[f0 + e];
    *(f32x4*)(x1 + i4) = o;
  }
}

// ---------------------------------------------------------------------------
// Fallback (non-cooperative) wrappers — same fixed gemm_phase.
// ---------------------------------------------------------------------------
template<int BN, bool AF32>
__global__ __launch_bounds__(512, 2)
void gemm64_k(const void* Ap, const u16* Bt, const int K, const int M,
              u16* outh)
{
  __shared__ char smem[2 * 8192 + 2 * 8 * (BN / 8) * 64 * 2];
  gemm_phase<64, BN, 64, AF32, 0, 1>(Ap, Bt, K, 0, K, M, nullptr, outh,
                                     smem, map64(blockIdx.x), 0, threadIdx.x);
}

template<int BN>
__global__ __launch_bounds__(512, 2)
void gemm128_k(const void* Ap, const u16* Bt, const int K, const int M,
               float* outf)
{
  __shared__ char smem[2 * 8192 + 3 * 8 * (BN / 8) * 32 * 2];
  int m0, kc; map128(blockIdx.x, m0, kc);
  gemm_phase<128, BN, 32, true, 3, 2>(Ap, Bt, K, kc * (K / 2), K / 2, M,
                                      outf, nullptr, smem, m0, kc, threadIdx.x);
}

__global__ __launch_bounds__(256)
void bn1_cast_k(const float* __restrict__ x, const float* __restrict__ g,
                const float* __restrict__ be, const float* __restrict__ rm,
                const float* __restrict__ rv, u16* __restrict__ out)
{
  const size_t i8 = ((size_t)blockIdx.x * 256 + threadIdx.x) * 8;
  const f32x4 v0 = *(const f32x4*)(x + i8);
  const f32x4 v1 = *(const f32x4*)(x + i8 + 4);
  const int f0 = (int)(i8 & 511);
  u16 u[8];
#pragma unroll
  for (int e = 0; e < 8; ++e) {
    const int f = f0 + e;
    const float sc = g[f] * rsqrtf(rv[f] + 1e-5f);
    const float v = (e < 4) ? v0[e] : v1[e - 4];
    u[e] = f2bf((v - rm[f]) * sc + be[f]);
  }
  uint4 o;
  o.x = (u32)u[0] | ((u32)u[1] << 16);
  o.y = (u32)u[2] | ((u32)u[3] << 16);
  o.z = (u32)u[4] | ((u32)u[5] << 16);
  o.w = (u32)u[6] | ((u32)u[7] << 16);
  *(uint4*)(out + i8) = o;
}

__global__ __launch_bounds__(256)
void tcvt_k(const float* __restrict__ in, u16* __restrict__ out, int rowlen)
{
  const int o = blockIdx.x * 256 + threadIdx.x;
  out[o] = f2bf(in[(size_t)(o & 511) * rowlen + (o >> 9)]);
}

__global__ __launch_bounds__(256)
void comb_bn_k(const float* __restrict__ P, const float* __restrict__ b1,
               const float* __restrict__ g2, const float* __restrict__ be2,
               const float* __restrict__ rm2, const float* __restrict__ rv2,
               float* __restrict__ out)
{
  const size_t i4 = ((size_t)blockIdx.x * 256 + threadIdx.x) * 4;
  const f32x4 p0 = *(const f32x4*)(P + i4);
  const f32x4 p1 = *(const f32x4*)(P + (size_t)16384 * 512 + i4);
  const int f0 = (int)(i4 & 511);
  f32x4 o;
#pragma unroll
  for (int e = 0; e < 4; ++e) {
    const int f = f0 + e;
    float s = fmaxf(p0[e] + p1[e] + b1[f], 0.f);
    const float sc = g2[f] * rsqrtf(rv2[f] + 1e-5f);
    o[e] = s * sc + (be2[f] - rm2[f] * sc);
  }
  *(f32x4*)(out + i4) = o;
}

__global__ __launch_bounds__(256)
void comb_k(const float* __restrict__ P, const float* __restrict__ b2,
            float* __restrict__ out)
{
  const size_t i4 = ((size_t)blockIdx.x * 256 + threadIdx.x) * 4;
  const f32x4 p0 = *(const f32x4*)(P + i4);
  const f32x4 p1 = *(const f32x4*)(P + (size_t)16384 * 128 + i4);
  const int f0 = (int)(i4 & 127);
  f32x4 o;
#pragma unroll
  for (int e = 0; e < 4; ++e) o[e] = p0[e] + p1[e] + b2[f0 + e];
  *(f32x4*)(out + i4) = o;
}

// ---------------------------------------------------------------------------
extern "C" void kernel_launch(void* const* d_in, const int* in_sizes, int n_in,
                              void* d_out, int out_size, void* d_ws, size_t ws_size,
                              hipStream_t stream)
{
  const float* x   = (const float*)d_in[0];
  const float* a   = (const float*)d_in[1];
  const float* w1  = (const float*)d_in[2];
  const float* b1  = (const float*)d_in[3];
  const float* w2  = (const float*)d_in[4];
  const float* b2  = (const float*)d_in[5];
  const float* g1  = (const float*)d_in[6];
  const float* be1 = (const float*)d_in[7];
  const float* rm1 = (const float*)d_in[8];
  const float* rv1 = (const float*)d_in[9];
  const float* g2  = (const float*)d_in[10];
  const float* be2 = (const float*)d_in[11];
  const float* rm2 = (const float*)d_in[12];
  const float* rv2 = (const float*)d_in[13];

  constexpr int N = 16384, F = 512, H = 512, C = 128;
  float* x1 = (float*)d_out;                      // [N][C]
  float* x2 = (float*)d_out + (size_t)N * C;      // [N][H]

  char* wsp = (char*)d_ws;
  u16* xb   = (u16*)wsp;   wsp += (size_t)N * F * 2;
  u16* t_t  = (u16*)wsp;   wsp += (size_t)H * N * 2;
  u16* z_t  = (u16*)wsp;   wsp += (size_t)C * N * 2;
  u16* w1t  = (u16*)wsp;   wsp += (size_t)H * F * 2;
  u16* w2t  = (u16*)wsp;   wsp += (size_t)C * H * 2;
  float* P2p = (float*)wsp; wsp += (size_t)2 * N * H * 4;
  float* P4p = (float*)wsp; wsp += (size_t)2 * N * C * 4;

  void* args[] = { (void*)&x, (void*)&a, (void*)&w1, (void*)&b1, (void*)&w2,
                   (void*)&b2, (void*)&g1, (void*)&be1, (void*)&rm1,
                   (void*)&rv1, (void*)&g2, (void*)&be2, (void*)&rm2,
                   (void*)&rv2, (void*)&xb, (void*)&w1t, (void*)&w2t,
                   (void*)&t_t, (void*)&z_t, (void*)&P2p, (void*)&P4p,
                   (void*)&x2, (void*)&x1 };

  hipError_t err = hipLaunchCooperativeKernel(
      (const void*)fused_gcn, dim3(256), dim3(512), args, 0, stream);

  if (err != hipSuccess) {
    bn1_cast_k<<<(N * F / 8) / 256, 256, 0, stream>>>(x, g1, be1, rm1, rv1, xb);
    tcvt_k<<<(F * H) / 256, 256, 0, stream>>>(w1, w1t, H);
    tcvt_k<<<(H * C) / 256, 256, 0, stream>>>(w2, w2t, C);
    gemm64_k<512, false><<<256, 512, 0, stream>>>(xb, w1t, F, N, t_t);
    gemm128_k<512><<<256, 512, 0, stream>>>(a, t_t, N, N, P2p);
    comb_bn_k<<<(N * H / 4) / 256, 256, 0, stream>>>(P2p, b1, g2, be2, rm2,
                                                     rv2, x2);
    gemm64_k<128, true><<<256, 512, 0, stream>>>(x2, w2t, H, N, z_t);
    gemm128_k<128><<<256, 512, 0, stream>>>(a, z_t, N, N, P4p);
    comb_k<<<(N * C / 4) / 256, 256, 0, stream>>>(P4p, b2, x1);
  }
}